// Round 2
// baseline (777.938 us; speedup 1.0000x reference)
//
#include <hip/hip_runtime.h>
#include <hip/hip_bf16.h>

#define TOKENS 16384
#define DMODEL 4096
#define NCH 8
#define CH 512
#define BM 64

typedef short s16x8 __attribute__((ext_vector_type(8)));
typedef float f32x4 __attribute__((ext_vector_type(4)));

__device__ __forceinline__ unsigned short f2bf(float f) {
    unsigned u = __float_as_uint(f);
    u += 0x7fffu + ((u >> 16) & 1u);
    return (unsigned short)(u >> 16);
}

// ---------------------------------------------------------------------------
// K0: weight prep. in: fp32 [n][c][d]  ->  out: bf16 [n][d][c] (transposed)
// ---------------------------------------------------------------------------
__global__ __launch_bounds__(256)
void wprep_kernel(const float* __restrict__ w1, const float* __restrict__ w2,
                  unsigned short* __restrict__ w1t, unsigned short* __restrict__ w2t)
{
    __shared__ float tile[32][33];
    const int which = blockIdx.z >> 3;
    const int n     = blockIdx.z & 7;
    const float*          src = (which ? w2 : w1) + (size_t)n * CH * CH;
    unsigned short*       dst = (which ? w2t : w1t) + (size_t)n * CH * CH;
    const int c0 = blockIdx.y * 32;
    const int d0 = blockIdx.x * 32;
    const int tx = threadIdx.x;
    const int ty = threadIdx.y;
#pragma unroll
    for (int i = 0; i < 32; i += 8)
        tile[ty + i][tx] = src[(size_t)(c0 + ty + i) * CH + d0 + tx];
    __syncthreads();
#pragma unroll
    for (int i = 0; i < 32; i += 8)
        dst[(size_t)(d0 + ty + i) * CH + c0 + tx] = f2bf(tile[tx][ty + i]);
}

// ---------------------------------------------------------------------------
// Double-buffered streamed-B GEMM over one 512-wide chunk (K = 512).
// A (BM x 512 bf16) in XOR-swizzled LDS; B = w[d][c] bf16 streamed from L2.
// Depth-1 prefetch, fully unrolled (static register indices only).
// ---------------------------------------------------------------------------
__device__ __forceinline__ void gemm_chunk(
    const unsigned short* __restrict__ wb,
    const unsigned char* lds,
    int nwoff, int l15, int kg,
    f32x4 (&acc)[4][8])
{
    s16x8 b0[8], b1[8], a0[4], a1[4];
    auto loadB = [&](s16x8 (&d)[8], int kt) {
#pragma unroll
        for (int ni = 0; ni < 8; ++ni)
            d[ni] = *(const s16x8*)(wb + (size_t)(nwoff + ni * 16 + l15) * CH + kt * 32 + kg * 8);
    };
    auto loadA = [&](s16x8 (&d)[4], int kt) {
#pragma unroll
        for (int mi = 0; mi < 4; ++mi) {
            int r = mi * 16 + l15;
            int byte = ((r * CH + kt * 32 + kg * 8) * 2) ^ ((r & 7) << 4);
            d[mi] = *(const s16x8*)(lds + byte);
        }
    };
    auto mm = [&](s16x8 (&a)[4], s16x8 (&b)[8]) {
#pragma unroll
        for (int ni = 0; ni < 8; ++ni)
#pragma unroll
            for (int mi = 0; mi < 4; ++mi)
                acc[mi][ni] = __builtin_amdgcn_mfma_f32_16x16x32_bf16(a[mi], b[ni], acc[mi][ni], 0, 0, 0);
    };

    loadB(b0, 0);
    loadA(a0, 0);
#pragma unroll
    for (int k2 = 0; k2 < 8; ++k2) {
        loadB(b1, 2 * k2 + 1);
        loadA(a1, 2 * k2 + 1);
        mm(a0, b0);                 // prefetched b1/a1 in flight under these MFMAs
        if (k2 < 7) {
            loadB(b0, 2 * k2 + 2);
            loadA(a0, 2 * k2 + 2);
        }
        mm(a1, b1);
    }
}

// ---------------------------------------------------------------------------
// K1: fused chunk MLP.  grid = 2048 (linear; n = bid&7 -> XCD affinity),
// block = 256 (4 waves), each wave owns a 128-wide N slice.
// MID_BF: store pre-LN mid as bf16 (ws) instead of fp32 (d_out).
// ---------------------------------------------------------------------------
template<bool MID_BF>
__global__ __launch_bounds__(256, 2)
void mlp_kernel(const float* __restrict__ x,
                const unsigned short* __restrict__ w1t,
                const unsigned short* __restrict__ w2t,
                const float* __restrict__ b1,
                const float* __restrict__ b2,
                void* __restrict__ midv)
{
    __shared__ unsigned char lds[BM * CH * 2];   // 64 KB, Xc then H1 (aliased)
    const int n    = blockIdx.x & 7;             // chunk -> XCD n (round-robin bid map)
    const int tile = blockIdx.x >> 3;
    const int tid  = threadIdx.x;
    const int wid  = tid >> 6;
    const int lane = tid & 63;
    const int row0 = tile * BM;

    // ---- stage Xc (fp32 -> bf16, swizzled) ----
    {
        const float* xc = x + (size_t)row0 * DMODEL + n * CH;
#pragma unroll
        for (int it = 0; it < 32; ++it) {
            int f = it * 256 + tid;
            int r = f >> 7;
            int c = (f & 127) << 2;
            const float4 v = *(const float4*)(xc + (size_t)r * DMODEL + c);
            unsigned lo = (unsigned)f2bf(v.x) | ((unsigned)f2bf(v.y) << 16);
            unsigned hi = (unsigned)f2bf(v.z) | ((unsigned)f2bf(v.w) << 16);
            int byte = ((r * CH + c) * 2) ^ ((r & 7) << 4);
            *(uint2*)(lds + byte) = make_uint2(lo, hi);
        }
    }
    __syncthreads();

    const int nwoff = wid * 128;
    const int l15   = lane & 15;
    const int kg    = lane >> 4;

    float b1v[8], b2v[8];
#pragma unroll
    for (int ni = 0; ni < 8; ++ni) {
        int col = nwoff + ni * 16 + l15;
        b1v[ni] = b1[n * CH + col];
        b2v[ni] = b2[n * CH + col];
    }

    f32x4 acc[4][8];
#pragma unroll
    for (int mi = 0; mi < 4; ++mi)
#pragma unroll
        for (int ni = 0; ni < 8; ++ni)
            acc[mi][ni] = (f32x4){0.f, 0.f, 0.f, 0.f};

    // ---- GEMM1 ----
    gemm_chunk(w1t + (size_t)n * CH * CH, lds, nwoff, l15, kg, acc);

    __syncthreads();   // all waves done reading Xc

    // ---- bias1 + exact GELU -> H1 bf16 into (aliased) LDS ----
#pragma unroll
    for (int mi = 0; mi < 4; ++mi)
#pragma unroll
        for (int ni = 0; ni < 8; ++ni)
#pragma unroll
            for (int r = 0; r < 4; ++r) {
                float v = acc[mi][ni][r] + b1v[ni];
                v = 0.5f * v * (1.0f + erff(v * 0.70710678118654752f));
                int row  = mi * 16 + kg * 4 + r;
                int col  = nwoff + ni * 16 + l15;
                int byte = ((row * CH + col) * 2) ^ ((row & 7) << 4);
                *(unsigned short*)(lds + byte) = f2bf(v);
            }
    __syncthreads();

#pragma unroll
    for (int mi = 0; mi < 4; ++mi)
#pragma unroll
        for (int ni = 0; ni < 8; ++ni)
            acc[mi][ni] = (f32x4){0.f, 0.f, 0.f, 0.f};

    // ---- GEMM2 ----
    gemm_chunk(w2t + (size_t)n * CH * CH, lds, nwoff, l15, kg, acc);

    // ---- epilogue: + b2 + residual x, store pre-LN mid ----
    const float* xr = x + (size_t)row0 * DMODEL + n * CH;
#pragma unroll
    for (int mi = 0; mi < 4; ++mi)
#pragma unroll
        for (int ni = 0; ni < 8; ++ni)
#pragma unroll
            for (int r = 0; r < 4; ++r) {
                int row = mi * 16 + kg * 4 + r;
                int col = nwoff + ni * 16 + l15;
                float v = acc[mi][ni][r] + b2v[ni] + xr[(size_t)row * DMODEL + col];
                size_t idx = (size_t)(row0 + row) * DMODEL + n * CH + col;
                if constexpr (MID_BF)
                    ((unsigned short*)midv)[idx] = f2bf(v);
                else
                    ((float*)midv)[idx] = v;
            }
}

// ---------------------------------------------------------------------------
// K2: LayerNorm. One block per row; each thread owns 16 contiguous elements.
// MID_BF: mid is bf16 in ws; else fp32 (in-place on d_out).
// ---------------------------------------------------------------------------
template<bool MID_BF>
__global__ __launch_bounds__(256)
void ln_kernel(const void* __restrict__ midv, float* __restrict__ out,
               const float* __restrict__ g, const float* __restrict__ bt)
{
    __shared__ float red[8];
    const int row = blockIdx.x;
    const int tid = threadIdx.x;
    const int c0  = tid * 16;

    float v[16];
    if constexpr (MID_BF) {
        const unsigned short* p = (const unsigned short*)midv + (size_t)row * DMODEL + c0;
        uint4 q0 = *(const uint4*)(p);
        uint4 q1 = *(const uint4*)(p + 8);
        unsigned w[8] = {q0.x, q0.y, q0.z, q0.w, q1.x, q1.y, q1.z, q1.w};
#pragma unroll
        for (int i = 0; i < 8; ++i) {
            v[2 * i]     = __uint_as_float(w[i] << 16);
            v[2 * i + 1] = __uint_as_float(w[i] & 0xffff0000u);
        }
    } else {
        const float* p = (const float*)midv + (size_t)row * DMODEL + c0;
#pragma unroll
        for (int i = 0; i < 4; ++i) {
            float4 q = *(const float4*)(p + i * 4);
            v[4 * i] = q.x; v[4 * i + 1] = q.y; v[4 * i + 2] = q.z; v[4 * i + 3] = q.w;
        }
    }

    float s = 0.f, ss = 0.f;
#pragma unroll
    for (int i = 0; i < 16; ++i) { s += v[i]; ss += v[i] * v[i]; }
#pragma unroll
    for (int o = 32; o > 0; o >>= 1) {
        s  += __shfl_xor(s, o, 64);
        ss += __shfl_xor(ss, o, 64);
    }
    const int wid = tid >> 6, lane = tid & 63;
    if (lane == 0) { red[wid] = s; red[4 + wid] = ss; }
    __syncthreads();
    s  = red[0] + red[1] + red[2] + red[3];
    ss = red[4] + red[5] + red[6] + red[7];
    const float mu   = s * (1.f / DMODEL);
    const float var  = ss * (1.f / DMODEL) - mu * mu;
    const float rstd = rsqrtf(var + 1e-5f);

    float* po = out + (size_t)row * DMODEL + c0;
#pragma unroll
    for (int i = 0; i < 4; ++i) {
        float4 gv = *(const float4*)(g  + c0 + i * 4);
        float4 bv = *(const float4*)(bt + c0 + i * 4);
        float4 o;
        o.x = (v[4 * i]     - mu) * rstd * gv.x + bv.x;
        o.y = (v[4 * i + 1] - mu) * rstd * gv.y + bv.y;
        o.z = (v[4 * i + 2] - mu) * rstd * gv.z + bv.z;
        o.w = (v[4 * i + 3] - mu) * rstd * gv.w + bv.w;
        *(float4*)(po + i * 4) = o;
    }
}

// ---------------------------------------------------------------------------
extern "C" void kernel_launch(void* const* d_in, const int* in_sizes, int n_in,
                              void* d_out, int out_size, void* d_ws, size_t ws_size,
                              hipStream_t stream)
{
    const float* x    = (const float*)d_in[0];
    const float* w1   = (const float*)d_in[1];
    const float* b1   = (const float*)d_in[2];
    const float* w2   = (const float*)d_in[3];
    const float* b2   = (const float*)d_in[4];
    const float* ln_g = (const float*)d_in[5];
    const float* ln_b = (const float*)d_in[6];
    float* out = (float*)d_out;

    unsigned short* w1t = (unsigned short*)d_ws;           // 4 MiB
    unsigned short* w2t = w1t + (size_t)NCH * CH * CH;     // 4 MiB

    const size_t wbytes   = (size_t)2 * NCH * CH * CH * 2; // 8 MiB
    const size_t midbytes = (size_t)TOKENS * DMODEL * 2;   // 128 MiB (bf16)
    const bool bf_mid = ws_size >= wbytes + midbytes;

    wprep_kernel<<<dim3(16, 16, 16), dim3(32, 8), 0, stream>>>(w1, w2, w1t, w2t);

    if (bf_mid) {
        unsigned short* mid = (unsigned short*)((char*)d_ws + wbytes);
        mlp_kernel<true><<<dim3(2048), dim3(256), 0, stream>>>(x, w1t, w2t, b1, b2, mid);
        ln_kernel<true><<<dim3(TOKENS), dim3(256), 0, stream>>>(mid, out, ln_g, ln_b);
    } else {
        mlp_kernel<false><<<dim3(2048), dim3(256), 0, stream>>>(x, w1t, w2t, b1, b2, out);
        ln_kernel<false><<<dim3(TOKENS), dim3(256), 0, stream>>>(out, out, ln_g, ln_b);
    }
}